// Round 7
// baseline (342.380 us; speedup 1.0000x reference)
//
#include <hip/hip_runtime.h>
#include <math.h>

// ParallelSMLSTMCell decomposed: never materialize C[B,S,D,D].
// B=8 S=512 F=32 D=64, window w=102. All f32.
// r7: k_main q-row-blocked (QR=4) with LDS vno tile + uniform ds_read_b128
// broadcasts (was: per-(b,s) blocks re-reading K/V tiles from L2 -> 70us,
// VALUBusy 29%). k_prep pre-transposes weights + C_prev (per-lane row reads
// were 64 cache lines/instr in k_proj/k_final). k_scalar_scan+k_csum merged.
#define BB 8
#define SS 512
#define FF 32
#define DD 64
#define WVOL 102
#define CH 16
#define NCH (SS / CH)  // 32 chunks
#define QR 4           // q-rows per k_main block

template<int CTRL, int RM, bool BC>
__device__ __forceinline__ float updpp(float oldv, float x) {
  return __int_as_float(__builtin_amdgcn_update_dpp(
      __float_as_int(oldv), __float_as_int(x), CTRL, RM, 0xF, BC));
}
__device__ __forceinline__ float rlane(float v, int l) {
  return __int_as_float(__builtin_amdgcn_readlane(__float_as_int(v), l));
}
__device__ __forceinline__ float dsum64(float x) {
  x += updpp<0x111, 0xF, true>(0.f, x);
  x += updpp<0x112, 0xF, true>(0.f, x);
  x += updpp<0x114, 0xF, true>(0.f, x);
  x += updpp<0x118, 0xF, true>(0.f, x);
  x += updpp<0x142, 0xF, true>(0.f, x);
  x += updpp<0x143, 0xF, true>(0.f, x);
  return rlane(x, 63);
}
__device__ __forceinline__ float dsum32(float x) {
  x += updpp<0x111, 0xF, true>(0.f, x);
  x += updpp<0x112, 0xF, true>(0.f, x);
  x += updpp<0x114, 0xF, true>(0.f, x);
  x += updpp<0x118, 0xF, true>(0.f, x);
  x += updpp<0x142, 0xF, true>(0.f, x);
  return rlane(x, 31);
}
__device__ __forceinline__ float dscan_add(float x) {
  x += updpp<0x111, 0xF, true>(0.f, x);
  x += updpp<0x112, 0xF, true>(0.f, x);
  x += updpp<0x114, 0xF, true>(0.f, x);
  x += updpp<0x118, 0xF, true>(0.f, x);
  x += updpp<0x142, 0xA, true>(0.f, x);
  x += updpp<0x143, 0xC, true>(0.f, x);
  return x;
}
__device__ __forceinline__ float dscan_mul(float x) {
  x *= updpp<0x111, 0xF, false>(1.f, x);
  x *= updpp<0x112, 0xF, false>(1.f, x);
  x *= updpp<0x114, 0xF, false>(1.f, x);
  x *= updpp<0x118, 0xF, false>(1.f, x);
  x *= updpp<0x142, 0xA, false>(1.f, x);
  x *= updpp<0x143, 0xC, false>(1.f, x);
  return x;
}

// -------- K0: transpose weights + C_prev; Cp row-sums (one-time prep) -------
__global__ void k_prep(const float* __restrict__ Cp,
                       const float* __restrict__ wq, const float* __restrict__ wk,
                       const float* __restrict__ wv, const float* __restrict__ wo,
                       const float* __restrict__ rw1,
                       float* __restrict__ CpT, float* __restrict__ wqT,
                       float* __restrict__ wkT, float* __restrict__ wvT,
                       float* __restrict__ woT, float* __restrict__ rw1T,
                       float* __restrict__ cpr, float* __restrict__ cpn2) {
  int blk = blockIdx.x; int lane = threadIdx.x;
  if (blk < BB) {
    int b = blk;
    const float* rowp = Cp + (size_t)(b * DD + lane) * DD;  // row lane (L1-hot)
    float rs = 0.f, r2 = 0.f;
#pragma unroll 8
    for (int j = 0; j < DD; ++j) {
      float c = rowp[j];
      rs += c; r2 = fmaf(c, c, r2);
      CpT[(size_t)(b * DD + j) * DD + lane] = c;  // coalesced write
    }
    cpr[b * DD + lane] = rs;
    float tot2 = dsum64(r2);
    if (lane == 0) cpn2[b] = tot2;
  } else {
    const float* src; float* dst;
    switch (blk - BB) {
      case 0: src = wq;  dst = wqT;  break;
      case 1: src = wk;  dst = wkT;  break;
      case 2: src = wv;  dst = wvT;  break;
      case 3: src = wo;  dst = woT;  break;
      default: src = rw1; dst = rw1T; break;
    }
#pragma unroll 8
    for (int f = 0; f < FF; ++f) dst[f * DD + lane] = src[lane * FF + f];
  }
}

// ---------------- K1: windowed std, one block per (b, s>=w-1) ----------------
__global__ void k_vol_std(const float* __restrict__ x, float* __restrict__ svraw) {
  int b = blockIdx.x; int s = WVOL - 1 + blockIdx.y;
  int lane = threadIdx.x; int f = lane & 31; int half = lane >> 5;
  const float* xb = x + (size_t)(b * SS) * FF + f;
  float wsum = 0.f, wsq = 0.f;
  int t0 = s - WVOL + 1 + half;
#pragma unroll 17
  for (int k = 0; k < WVOL / 2; ++k) {
    float xv = xb[(t0 + 2 * k) * FF];
    wsum += xv; wsq = fmaf(xv, xv, wsq);
  }
  wsum += __shfl_xor(wsum, 32); wsq += __shfl_xor(wsq, 32);
  float var = (wsq - wsum * wsum * (1.f / WVOL)) * (1.f / (WVOL - 1));
  float sd = sqrtf(fmaxf(var, 0.f));
  float m = dsum64(sd) * 0.5f * (1.f / FF);  // halves duplicated -> /2
  if (lane == 0) svraw[b * SS + s] = m;
}

// ---------------- K2: per-(b,s) LN + projections + gates + zc ----------------
__global__ void k_proj(const float* __restrict__ x, const float* __restrict__ m_prev,
                       const float* __restrict__ CpT,
                       const float* __restrict__ ln_in_g, const float* __restrict__ ln_in_b,
                       const float* __restrict__ wqT, const float* __restrict__ bq,
                       const float* __restrict__ wkT, const float* __restrict__ bk,
                       const float* __restrict__ wvT, const float* __restrict__ bv,
                       const float* __restrict__ wi, const float* __restrict__ bi,
                       const float* __restrict__ wf, const float* __restrict__ bf,
                       const float* __restrict__ woT, const float* __restrict__ bo,
                       const float* __restrict__ rw1T, const float* __restrict__ rd_b1,
                       const float* __restrict__ rd_g, const float* __restrict__ rd_be,
                       const float* __restrict__ rd_w2, const float* __restrict__ rd_b2,
                       float* __restrict__ qo, float* __restrict__ kno, float* __restrict__ vno,
                       float* __restrict__ iko, float* __restrict__ oo,
                       float* __restrict__ knT, float* __restrict__ vnT,
                       float* __restrict__ cg_a, float* __restrict__ fg_a,
                       float* __restrict__ mf_a, float* __restrict__ cks_a,
                       float* __restrict__ qsum_a, float* __restrict__ zc) {
  int bs = blockIdx.x; int b = bs / SS; int s = bs % SS;
  int lane = threadIdx.x;
  __shared__ float xs[FF];
  __shared__ float ks[DD];
  float xv = (lane < FF) ? x[bs * FF + lane] : 0.f;
  float s1x = dsum32(xv);
  float s2x = dsum32(xv * xv);
  if (lane < FF) {
    float mu = s1x * (1.f / FF);
    float var = s2x * (1.f / FF) - mu * mu;
    xs[lane] = (xv - mu) * rsqrtf(var + 1e-5f) * ln_in_g[lane] + ln_in_b[lane];
  }
  __syncthreads();
  int d = lane;
  float aq = bq[d], ak = bk[d], av = bv[d], ao = bo[d], at = rd_b1[d];
#pragma unroll
  for (int f = 0; f < FF; ++f) {
    float xf = xs[f];
    aq = fmaf(xf, wqT[f * DD + d], aq);   // coalesced (transposed)
    ak = fmaf(xf, wkT[f * DD + d], ak);
    av = fmaf(xf, wvT[f * DD + d], av);
    ao = fmaf(xf, woT[f * DD + d], ao);
    at = fmaf(xf, rw1T[f * DD + d], at);
  }
  float pit = (lane < FF) ? xs[lane] * wi[lane] : 0.f;
  float pft = (lane < FF) ? xs[lane] * wf[lane] : 0.f;
  float itv = dsum32(pit) + bi[0];
  float ftv = dsum32(pft) + bf[0];
  // regime head: LN(D) -> gelu(exact) -> 4 logits -> softmax[0]
  float s1 = dsum64(at), s2 = dsum64(at * at);
  float mu = s1 * (1.f / DD);
  float var = s2 * (1.f / DD) - mu * mu;
  float tn = (at - mu) * rsqrtf(var + 1e-5f) * rd_g[d] + rd_be[d];
  float ge = 0.5f * tn * (1.f + erff(tn * 0.70710678118654752f));
  float l0 = dsum64(ge * rd_w2[0 * DD + d]) + rd_b2[0];
  float l1 = dsum64(ge * rd_w2[1 * DD + d]) + rd_b2[1];
  float l2 = dsum64(ge * rd_w2[2 * DD + d]) + rd_b2[2];
  float l3 = dsum64(ge * rd_w2[3 * DD + d]) + rd_b2[3];
  float mx = fmaxf(fmaxf(l0, l1), fmaxf(l2, l3));
  float e0 = expf(l0 - mx), e1 = expf(l1 - mx), e2 = expf(l2 - mx), e3 = expf(l3 - mx);
  float mfv = e0 / (e0 + e1 + e2 + e3);
  // normalize k, v
  float kd = ak * 0.125f;
  float kk = dsum64(kd * kd);
  float knd = kd * (8.f / (sqrtf(kk) + 1e-12f));
  float vv = dsum64(av * av);
  float vnd = av * (8.f / (sqrtf(vv) + 1e-6f));
  float ksum = dsum64(knd);
  float qsum = dsum64(aq);
  // stabilized gates
  float mp = fminf(fmaxf(m_prev[b], -100.f), 100.f);
  float mt = fmaxf(ftv, mp + ftv);
  float ig = expf(fminf(fmaxf(itv - mt, -15.f), 15.f));
  float fg = expf(fminf(fmaxf(ftv + mp - mt, -15.f), 15.f));
  float cg = fminf(ig, 1.f);
  qo[bs * DD + d] = aq;
  kno[bs * DD + d] = knd;
  vno[bs * DD + d] = vnd;
  iko[bs * DD + d] = ig * kd;
  oo[bs * DD + d] = 1.f / (1.f + expf(-ao));
  knT[(b * DD + d) * SS + s] = knd;
  vnT[(b * DD + d) * SS + s] = vnd;
  // fused zc = cg * vn^T Cp kn  (CpT -> coalesced)
  ks[d] = knd;
  __syncthreads();
  float acc = 0.f;
  const float* cpt = CpT + (size_t)b * DD * DD;
#pragma unroll 8
  for (int j = 0; j < DD; ++j) acc = fmaf(cpt[j * DD + d], ks[j], acc);
  float z = dsum64(vnd * acc);
  if (lane == 0) {
    cg_a[bs] = cg; fg_a[bs] = fg; mf_a[bs] = mfv;
    cks_a[bs] = cg * ksum; qsum_a[bs] = qsum;
    zc[bs] = cg * z;
  }
}

// -------- K3: O(S^2) linear-attn p2 + Gram rho; QR q-rows per 1-wave block --
__global__ void k_main(const float* __restrict__ qo, const float* __restrict__ kno,
                       const float* __restrict__ vno,
                       const float* __restrict__ knT, const float* __restrict__ vnT,
                       const float* __restrict__ cg_a,
                       float* __restrict__ p2, float* __restrict__ rho) {
  int blk = blockIdx.x;
  int b = blk >> 7;                 // 128 qtiles of QR=4 rows per b
  int q0 = blk & 127;
  int qt = (q0 & 1) ? (127 - (q0 >> 1)) : (q0 >> 1);  // light/heavy interleave
  int lane = threadIdx.x;
  int s0 = qt * QR;
  __shared__ float vls[64][DD];     // vno kv-tile [t][d], 16KB
  __shared__ float qs[QR][DD], kss[QR][DD], vss[QR][DD];  // 3KB row broadcasts
  __shared__ float wl[64];
#pragma unroll
  for (int r = 0; r < QR; ++r) {
    int base = (b * SS + s0 + r) * DD + lane;
    qs[r][lane] = qo[base]; kss[r][lane] = kno[base]; vss[r][lane] = vno[base];
  }
  float p2a[QR], rhoa[QR], A[QR], G1[QR], G2[QR];
#pragma unroll
  for (int r = 0; r < QR; ++r) { p2a[r] = 0.f; rhoa[r] = 0.f; }
  int tmax = s0 + QR - 1;
  for (int t0 = 0; t0 <= tmax; t0 += 64) {
    int t = t0 + lane;
    // stage vno kv-tile (coalesced)
#pragma unroll 8
    for (int r = 0; r < 64; ++r) vls[r][lane] = vno[(b * SS + t0 + r) * DD + lane];
#pragma unroll
    for (int r = 0; r < QR; ++r) { A[r] = 0.f; G1[r] = 0.f; G2[r] = 0.f; }
    const float* kTp = knT + (size_t)b * DD * SS + t;
    const float* vTp = vnT + (size_t)b * DD * SS + t;
    for (int j = 0; j < DD; j += 4) {
      float kv0 = kTp[(j + 0) * SS], kv1 = kTp[(j + 1) * SS];
      float kv2 = kTp[(j + 2) * SS], kv3 = kTp[(j + 3) * SS];
      float vv0 = vTp[(j + 0) * SS], vv1 = vTp[(j + 1) * SS];
      float vv2 = vTp[(j + 2) * SS], vv3 = vTp[(j + 3) * SS];
#pragma unroll
      for (int r = 0; r < QR; ++r) {
        float4 qq = *(const float4*)&qs[r][j];    // uniform ds_read_b128
        float4 kk = *(const float4*)&kss[r][j];
        float4 vv = *(const float4*)&vss[r][j];
        A[r] = fmaf(kv0, qq.x, A[r]); A[r] = fmaf(kv1, qq.y, A[r]);
        A[r] = fmaf(kv2, qq.z, A[r]); A[r] = fmaf(kv3, qq.w, A[r]);
        G1[r] = fmaf(kv0, kk.x, G1[r]); G1[r] = fmaf(kv1, kk.y, G1[r]);
        G1[r] = fmaf(kv2, kk.z, G1[r]); G1[r] = fmaf(kv3, kk.w, G1[r]);
        G2[r] = fmaf(vv0, vv.x, G2[r]); G2[r] = fmaf(vv1, vv.y, G2[r]);
        G2[r] = fmaf(vv2, vv.z, G2[r]); G2[r] = fmaf(vv3, vv.w, G2[r]);
      }
    }
    float cgt = cg_a[b * SS + t];
#pragma unroll
    for (int r = 0; r < QR; ++r) {
      int s = s0 + r;
      float wr = (t < s) ? 2.f : (t == s ? 1.f : 0.f);
      rhoa[r] = fmaf(wr * cgt, G1[r] * G2[r], rhoa[r]);  // per-lane partial
    }
#pragma unroll
    for (int r = 0; r < QR; ++r) {
      int s = s0 + r;
      wl[lane] = (t <= s) ? cgt * A[r] : 0.f;  // single wave: lgkmcnt orders
      float acc = p2a[r];
#pragma unroll 4
      for (int tt = 0; tt < 64; tt += 4) {
        float4 w4 = *(const float4*)&wl[tt];   // uniform ds_read_b128
        acc = fmaf(w4.x, vls[tt + 0][lane], acc);
        acc = fmaf(w4.y, vls[tt + 1][lane], acc);
        acc = fmaf(w4.z, vls[tt + 2][lane], acc);
        acc = fmaf(w4.w, vls[tt + 3][lane], acc);
      }
      p2a[r] = acc;
    }
  }
#pragma unroll
  for (int r = 0; r < QR; ++r) p2[(b * SS + s0 + r) * DD + lane] = p2a[r];
#pragma unroll
  for (int r = 0; r < QR; ++r) {
    float rr = dsum64(rhoa[r]);
    float cgs = cg_a[b * SS + s0 + r];
    if (lane == 0) rho[b * SS + s0 + r] = cgs * rr;
  }
}

// ---- K4: merged: blocks 0..7 scalar scans + vol-norm; blocks 8+ chunk sums --
__global__ void k_post(const float* __restrict__ fg_a, const float* __restrict__ zc,
                       const float* __restrict__ rho, const float* __restrict__ svraw,
                       const float* __restrict__ ik, const float* __restrict__ vno,
                       const float* __restrict__ cks_a,
                       float* __restrict__ fcum, float* __restrict__ cpd,
                       float* __restrict__ sn2, float* __restrict__ sv,
                       float* __restrict__ csn, float* __restrict__ csr) {
  int blk = blockIdx.x; int lane = threadIdx.x;
  if (blk < BB) {
    int b = blk;
    // vol normalize
    float m0 = svraw[b * SS + WVOL - 1];
    float vals[8]; float part = 0.f;
#pragma unroll
    for (int c = 0; c < 8; ++c) {
      int idx = c * 64 + lane;
      float v = (idx < WVOL - 1) ? m0 : svraw[b * SS + idx];
      vals[c] = v; part += v;
    }
    float tot = dsum64(part);
    float inv = 1.f / (tot * (1.f / SS) + 1e-6f);
#pragma unroll
    for (int c = 0; c < 8; ++c) sv[b * SS + c * 64 + lane] = vals[c] * inv;
    // chunked inclusive scans: product(fg), sum(zc), sum(rho)
    float cf = 1.f, cz = 0.f, crr = 0.f;
    for (int c = 0; c < 8; ++c) {
      int bs = b * SS + c * 64 + lane;
      float f = dscan_mul(fg_a[bs]) * cf;
      float z = dscan_add(zc[bs]) + cz;
      float r = dscan_add(rho[bs]) + crr;
      fcum[bs] = f; cpd[bs] = z; sn2[bs] = r;
      cf = rlane(f, 63); cz = rlane(z, 63); crr = rlane(r, 63);
    }
  } else {
    int blk2 = blk - BB; int b = blk2 / NCH; int w = blk2 % NCH; int d = lane;
    float na = 0.f, ra = 0.f;
#pragma unroll
    for (int t = 0; t < CH; ++t) {
      int bs = b * SS + w * CH + t;
      na += ik[bs * DD + d];
      ra = fmaf(cks_a[bs], vno[bs * DD + d], ra);
    }
    csn[blk2 * DD + d] = na; csr[blk2 * DD + d] = ra;
  }
}

__global__ void k_scan_apply(const float* __restrict__ ik, const float* __restrict__ vno,
                             const float* __restrict__ cks_a,
                             const float* __restrict__ csn, const float* __restrict__ csr,
                             float* __restrict__ nacc, float* __restrict__ racc) {
  int blk = blockIdx.x; int b = blk / NCH; int w = blk % NCH; int d = threadIdx.x;
  float na = 0.f, ra = 0.f;
  for (int w2 = 0; w2 < w; ++w2) {
    na += csn[(b * NCH + w2) * DD + d];
    ra += csr[(b * NCH + w2) * DD + d];
  }
#pragma unroll
  for (int t = 0; t < CH; ++t) {
    int bs = b * SS + w * CH + t;
    na += ik[bs * DD + d];
    ra = fmaf(cks_a[bs], vno[bs * DD + d], ra);
    nacc[bs * DD + d] = na;
    racc[bs * DD + d] = ra;
  }
}

// ---------------- K6: SSM scan, one wave per (b, row i); tight chain ---------
__global__ void k_ssm(const float* __restrict__ fcum, const float* __restrict__ racc,
                      const float* __restrict__ cpr, const float* __restrict__ sv,
                      const float* __restrict__ log_lam, const float* __restrict__ log_b,
                      const float* __restrict__ cvec,
                      const float* __restrict__ log_step, const float* __restrict__ vol_gate,
                      const float* __restrict__ ln_g, const float* __restrict__ ln_b,
                      float* __restrict__ ysT) {
  int blk = blockIdx.x; int b = blk >> 6; int i = blk & 63;
  int n = threadIdx.x;
  float st = expf(log_step[0]);
  float lam = -expf(log_lam[n]);
  float ad = (2.f + st * lam) / (2.f - st * lam);
  float bd = st * (1.f + ad) * expf(log_b[n]) * 0.5f;
  float vg = 1.f / (1.f + expf(-vol_gate[n]));
  float g = ln_g[n], be = ln_b[n], cn = cvec[n];
  float cprv = cpr[b * DD + i];
  float u[8], w[8];
#pragma unroll
  for (int c = 0; c < 8; ++c) {
    int s = c * 64 + n; int bs = b * SS + s;
    u[c] = fmaf(fcum[bs], cprv, racc[(size_t)bs * DD + i]) * (1.f / DD);
    w[c] = sv[bs];
  }
  float h = 0.f;
#pragma unroll
  for (int c = 0; c < 8; ++c) {
    float yout = 0.f;
#pragma unroll 4
    for (int t = 0; t < 64; ++t) {
      float uu = rlane(u[c], t);
      float vv = rlane(w[c], t);
      float bdu = bd * uu;
      float rden = __builtin_amdgcn_rcpf(fmaf(vg, vv, 1.f));
      float grden = g * rden, berden = be * rden;
      float ht = fmaf(ad, h, bdu);
      float p1 = ht, p2 = ht * ht;
      p1 += updpp<0x111, 0xF, true>(0.f, p1); p2 += updpp<0x111, 0xF, true>(0.f, p2);
      p1 += updpp<0x112, 0xF, true>(0.f, p1); p2 += updpp<0x112, 0xF, true>(0.f, p2);
      p1 += updpp<0x114, 0xF, true>(0.f, p1); p2 += updpp<0x114, 0xF, true>(0.f, p2);
      p1 += updpp<0x118, 0xF, true>(0.f, p1); p2 += updpp<0x118, 0xF, true>(0.f, p2);
      p1 += updpp<0x142, 0xF, true>(0.f, p1); p2 += updpp<0x142, 0xF, true>(0.f, p2);
      p1 += updpp<0x143, 0xF, true>(0.f, p1); p2 += updpp<0x143, 0xF, true>(0.f, p2);
      float s1 = rlane(p1, 63), s2 = rlane(p2, 63);
      float mu = s1 * (1.f / DD);
      float r2m = fmaf(-mu, s1, s2);
      float arg = fmaxf(fmaf(r2m, 1.f / DD, 1e-5f), 1e-5f);
      float irs = __builtin_amdgcn_rsqf(arg);
      float hv = fmaf((ht - mu) * grden, irs, berden);
      h = hv;
      float y = cn * hv;
      y += updpp<0x111, 0xF, true>(0.f, y);
      y += updpp<0x112, 0xF, true>(0.f, y);
      y += updpp<0x114, 0xF, true>(0.f, y);
      y += updpp<0x118, 0xF, true>(0.f, y);
      y += updpp<0x142, 0xF, true>(0.f, y);
      y += updpp<0x143, 0xF, true>(0.f, y);
      float su = rlane(y, 63);
      yout = (n == t) ? su : yout;
    }
    ysT[(size_t)(b * DD + i) * SS + c * 64 + n] = yout;  // coalesced
  }
}

// ---------------- K7: final readout ----------------
__global__ void k_final(const float* __restrict__ qo, const float* __restrict__ oo,
                        const float* __restrict__ p2, const float* __restrict__ racc,
                        const float* __restrict__ nacc, const float* __restrict__ ysT,
                        const float* __restrict__ CpT, const float* __restrict__ cpr,
                        const float* __restrict__ cpn2,
                        const float* __restrict__ fcum, const float* __restrict__ cpd,
                        const float* __restrict__ sn2,
                        const float* __restrict__ mf_a, const float* __restrict__ qsum_a,
                        const float* __restrict__ n_prev,
                        const float* __restrict__ ssm_log_d, const float* __restrict__ ssm_alpha,
                        const float* __restrict__ ln_mem_g, const float* __restrict__ ln_mem_b,
                        float* __restrict__ out) {
  int bs = blockIdx.x; int b = bs / SS; int s = bs % SS;
  int i = threadIdx.x;
  __shared__ float qv[DD];
  float qi = qo[bs * DD + i];
  qv[i] = qi;
  __syncthreads();
  float P1 = 0.f;
  const float* cpt = CpT + (size_t)b * DD * DD;
#pragma unroll 8
  for (int j = 0; j < DD; ++j) P1 = fmaf(cpt[j * DD + i], qv[j], P1);  // coalesced
  float fc = fcum[bs];
  float p = fmaf(fc, P1, p2[bs * DD + i]);
  float r = fmaf(fc, cpr[b * DD + i], racc[bs * DD + i]);
  float R2 = fc * fc * cpn2[b] + 2.f * fc * cpd[bs] + sn2[bs];
  float al = 1.f / (1.f + expf(-ssm_alpha[0]));
  float kap = al + (1.f - al) * expf(ssm_log_d[0]);
  float mfv = mf_a[bs];
  float beta = 1.f + mfv * (kap - 1.f);
  float gam = mfv * (1.f - al);
  float y = ysT[(size_t)(b * DD + i) * SS + s];
  float syr = dsum64(y * r);
  float sy2 = dsum64(y * y);
  float nrm2 = fmaxf(beta * beta * R2 + 2.f * beta * gam * syr + gam * gam * (float)DD * sy2, 0.f);
  float scale = 8.f / (sqrtf(nrm2) + 1e-6f);
  float nt = fmaf(fc, n_prev[b * DD + i], nacc[bs * DD + i]);
  float ndp = dsum64(nt * qi);
  float denom = fmaxf(fabsf(ndp), 1.f);
  float hh = scale * (fmaf(beta, p, gam * y * qsum_a[bs])) / denom;
  float s1 = dsum64(hh), s2 = dsum64(hh * hh);
  float mu = s1 * (1.f / DD);
  float var = fmaxf(s2 * (1.f / DD) - mu * mu, 0.f);
  float o = (hh - mu) * rsqrtf(var + 1e-5f) * ln_mem_g[i] + ln_mem_b[i];
  out[bs * DD + i] = oo[bs * DD + i] * o;
}

extern "C" void kernel_launch(void* const* d_in, const int* in_sizes, int n_in,
                              void* d_out, int out_size, void* d_ws, size_t ws_size,
                              hipStream_t stream) {
  const float* x        = (const float*)d_in[0];
  const float* C_prev   = (const float*)d_in[1];
  const float* n_prev   = (const float*)d_in[2];
  const float* m_prev   = (const float*)d_in[3];
  const float* ln_in_g  = (const float*)d_in[4];
  const float* ln_in_b  = (const float*)d_in[5];
  const float* wq = (const float*)d_in[6];  const float* bq = (const float*)d_in[7];
  const float* wk = (const float*)d_in[8];  const float* bk = (const float*)d_in[9];
  const float* wv = (const float*)d_in[10]; const float* bv = (const float*)d_in[11];
  const float* wi = (const float*)d_in[12]; const float* bi = (const float*)d_in[13];
  const float* wf = (const float*)d_in[14]; const float* bf = (const float*)d_in[15];
  const float* wo = (const float*)d_in[16]; const float* bo = (const float*)d_in[17];
  const float* rd_w1 = (const float*)d_in[18]; const float* rd_b1 = (const float*)d_in[19];
  const float* rd_g  = (const float*)d_in[20]; const float* rd_be = (const float*)d_in[21];
  const float* rd_w2 = (const float*)d_in[22]; const float* rd_b2 = (const float*)d_in[23];
  const float* ssm_log_lam  = (const float*)d_in[24];
  const float* ssm_log_b    = (const float*)d_in[25];
  const float* ssm_c        = (const float*)d_in[26];
  const float* ssm_log_d    = (const float*)d_in[27];
  const float* ssm_log_step = (const float*)d_in[28];
  const float* ssm_vol_gate = (const float*)d_in[29];
  const float* ssm_alpha    = (const float*)d_in[30];
  const float* ssm_ln_g     = (const float*)d_in[31];
  const float* ssm_ln_b     = (const float*)d_in[32];
  const float* ln_mem_g     = (const float*)d_in[33];
  const float* ln_mem_b     = (const float*)d_in[34];
  float* out = (float*)d_out;

  float* W = (float*)d_ws;
  size_t o0 = 0;
  const size_t BS = (size_t)BB * SS, BSD = BS * DD;
  float* sv    = W + o0; o0 += BS;
  float* svraw = W + o0; o0 += BS;
  float* qo   = W + o0; o0 += BSD;
  float* kno  = W + o0; o0 += BSD;
  float* vno  = W + o0; o0 += BSD;
  float* iko  = W + o0; o0 += BSD;
  float* oo   = W + o0; o0 += BSD;
  float* knT  = W + o0; o0 += BSD;
  float* vnT  = W + o0; o0 += BSD;
  float* p2   = W + o0; o0 += BSD;
  float* racc = W + o0; o0 += BSD;
  float* nacc = W + o0; o0 += BSD;
  float* ysT  = W + o0; o0 += BSD;
  float* cg_a = W + o0; o0 += BS;
  float* fg_a = W + o0; o0 += BS;
  float* mf_a = W + o0; o0 += BS;
  float* cks  = W + o0; o0 += BS;
  float* qsum = W + o0; o0 += BS;
  float* zc   = W + o0; o0 += BS;
  float* fcum = W + o0; o0 += BS;
  float* cpd  = W + o0; o0 += BS;
  float* rho  = W + o0; o0 += BS;
  float* sn2  = W + o0; o0 += BS;
  float* cpr  = W + o0; o0 += (size_t)BB * DD;
  float* cpn2 = W + o0; o0 += BB;
  float* csn  = W + o0; o0 += (size_t)BB * NCH * DD;
  float* csr  = W + o0; o0 += (size_t)BB * NCH * DD;
  float* CpT  = W + o0; o0 += (size_t)BB * DD * DD;
  float* wqT  = W + o0; o0 += (size_t)FF * DD;
  float* wkT  = W + o0; o0 += (size_t)FF * DD;
  float* wvT  = W + o0; o0 += (size_t)FF * DD;
  float* woT  = W + o0; o0 += (size_t)FF * DD;
  float* rw1T = W + o0; o0 += (size_t)FF * DD;

  hipLaunchKernelGGL(k_prep, dim3(BB + 5), dim3(64), 0, stream,
                     C_prev, wq, wk, wv, wo, rd_w1,
                     CpT, wqT, wkT, wvT, woT, rw1T, cpr, cpn2);
  hipLaunchKernelGGL(k_vol_std, dim3(BB, SS - WVOL + 1), dim3(64), 0, stream, x, svraw);
  hipLaunchKernelGGL(k_proj, dim3(BB * SS), dim3(64), 0, stream,
                     x, m_prev, CpT, ln_in_g, ln_in_b, wqT, bq, wkT, bk, wvT, bv, wi, bi,
                     wf, bf, woT, bo, rw1T, rd_b1, rd_g, rd_be, rd_w2, rd_b2,
                     qo, kno, vno, iko, oo, knT, vnT, cg_a, fg_a, mf_a, cks, qsum, zc);
  hipLaunchKernelGGL(k_main, dim3(BB * 128), dim3(64), 0, stream,
                     qo, kno, vno, knT, vnT, cg_a, p2, rho);
  hipLaunchKernelGGL(k_post, dim3(BB + BB * NCH), dim3(64), 0, stream,
                     fg_a, zc, rho, svraw, iko, vno, cks,
                     fcum, cpd, sn2, sv, csn, csr);
  hipLaunchKernelGGL(k_scan_apply, dim3(BB * NCH), dim3(64), 0, stream,
                     iko, vno, cks, csn, csr, nacc, racc);
  hipLaunchKernelGGL(k_ssm, dim3(BB * DD), dim3(64), 0, stream,
                     fcum, racc, cpr, sv, ssm_log_lam, ssm_log_b, ssm_c,
                     ssm_log_step, ssm_vol_gate, ssm_ln_g, ssm_ln_b, ysT);
  hipLaunchKernelGGL(k_final, dim3(BB * SS), dim3(64), 0, stream,
                     qo, oo, p2, racc, nacc, ysT, CpT, cpr, cpn2, fcum, cpd, sn2,
                     mf_a, qsum, n_prev, ssm_log_d, ssm_alpha, ln_mem_g, ln_mem_b, out);
}

// Round 8
// 295.054 us; speedup vs baseline: 1.1604x; 1.1604x over previous
//
#include <hip/hip_runtime.h>
#include <math.h>

// ParallelSMLSTMCell decomposed: never materialize C[B,S,D,D].
// B=8 S=512 F=32 D=64, window w=102. All f32.
// r8: O(S^2) phase as tiled-GEMM pair: k_qk (A/KK/VV over 32x32 causal tile
// pairs, writes masked W + rho atomics) + k_pv (p2 = W @ vn, K-split).
// r7 lesson: QR-blocking at 1024 one-wave blocks -> 2 waves/CU, latency-bound
// (77us, VALU 14%). GEMM tiling keeps reuse AND ~4 waves/SIMD.
#define BB 8
#define SS 512
#define FF 32
#define DD 64
#define WVOL 102
#define CH 16
#define NCH (SS / CH)  // 32 chunks

template<int CTRL, int RM, bool BC>
__device__ __forceinline__ float updpp(float oldv, float x) {
  return __int_as_float(__builtin_amdgcn_update_dpp(
      __float_as_int(oldv), __float_as_int(x), CTRL, RM, 0xF, BC));
}
__device__ __forceinline__ float rlane(float v, int l) {
  return __int_as_float(__builtin_amdgcn_readlane(__float_as_int(v), l));
}
__device__ __forceinline__ float dsum64(float x) {
  x += updpp<0x111, 0xF, true>(0.f, x);
  x += updpp<0x112, 0xF, true>(0.f, x);
  x += updpp<0x114, 0xF, true>(0.f, x);
  x += updpp<0x118, 0xF, true>(0.f, x);
  x += updpp<0x142, 0xF, true>(0.f, x);
  x += updpp<0x143, 0xF, true>(0.f, x);
  return rlane(x, 63);
}
__device__ __forceinline__ float dsum32(float x) {
  x += updpp<0x111, 0xF, true>(0.f, x);
  x += updpp<0x112, 0xF, true>(0.f, x);
  x += updpp<0x114, 0xF, true>(0.f, x);
  x += updpp<0x118, 0xF, true>(0.f, x);
  x += updpp<0x142, 0xF, true>(0.f, x);
  return rlane(x, 31);
}
// sum over the 16-lane DPP row; lane (row*16+15) holds the row sum
__device__ __forceinline__ float dsum16(float x) {
  x += updpp<0x111, 0xF, true>(0.f, x);
  x += updpp<0x112, 0xF, true>(0.f, x);
  x += updpp<0x114, 0xF, true>(0.f, x);
  x += updpp<0x118, 0xF, true>(0.f, x);
  return x;
}
__device__ __forceinline__ float dscan_add(float x) {
  x += updpp<0x111, 0xF, true>(0.f, x);
  x += updpp<0x112, 0xF, true>(0.f, x);
  x += updpp<0x114, 0xF, true>(0.f, x);
  x += updpp<0x118, 0xF, true>(0.f, x);
  x += updpp<0x142, 0xA, true>(0.f, x);
  x += updpp<0x143, 0xC, true>(0.f, x);
  return x;
}
__device__ __forceinline__ float dscan_mul(float x) {
  x *= updpp<0x111, 0xF, false>(1.f, x);
  x *= updpp<0x112, 0xF, false>(1.f, x);
  x *= updpp<0x114, 0xF, false>(1.f, x);
  x *= updpp<0x118, 0xF, false>(1.f, x);
  x *= updpp<0x142, 0xA, false>(1.f, x);
  x *= updpp<0x143, 0xC, false>(1.f, x);
  return x;
}

// -------- K0: transpose weights + C_prev; Cp row-sums (one-time prep) -------
__global__ void k_prep(const float* __restrict__ Cp,
                       const float* __restrict__ wq, const float* __restrict__ wk,
                       const float* __restrict__ wv, const float* __restrict__ wo,
                       const float* __restrict__ rw1,
                       float* __restrict__ CpT, float* __restrict__ wqT,
                       float* __restrict__ wkT, float* __restrict__ wvT,
                       float* __restrict__ woT, float* __restrict__ rw1T,
                       float* __restrict__ cpr, float* __restrict__ cpn2) {
  int blk = blockIdx.x; int lane = threadIdx.x;
  if (blk < BB) {
    int b = blk;
    const float* rowp = Cp + (size_t)(b * DD + lane) * DD;
    float rs = 0.f, r2 = 0.f;
#pragma unroll 8
    for (int j = 0; j < DD; ++j) {
      float c = rowp[j];
      rs += c; r2 = fmaf(c, c, r2);
      CpT[(size_t)(b * DD + j) * DD + lane] = c;
    }
    cpr[b * DD + lane] = rs;
    float tot2 = dsum64(r2);
    if (lane == 0) cpn2[b] = tot2;
  } else {
    const float* src; float* dst;
    switch (blk - BB) {
      case 0: src = wq;  dst = wqT;  break;
      case 1: src = wk;  dst = wkT;  break;
      case 2: src = wv;  dst = wvT;  break;
      case 3: src = wo;  dst = woT;  break;
      default: src = rw1; dst = rw1T; break;
    }
#pragma unroll 8
    for (int f = 0; f < FF; ++f) dst[f * DD + lane] = src[lane * FF + f];
  }
}

// ---------------- K1: windowed std, one block per (b, s>=w-1) ----------------
__global__ void k_vol_std(const float* __restrict__ x, float* __restrict__ svraw) {
  int b = blockIdx.x; int s = WVOL - 1 + blockIdx.y;
  int lane = threadIdx.x; int f = lane & 31; int half = lane >> 5;
  const float* xb = x + (size_t)(b * SS) * FF + f;
  float wsum = 0.f, wsq = 0.f;
  int t0 = s - WVOL + 1 + half;
#pragma unroll 17
  for (int k = 0; k < WVOL / 2; ++k) {
    float xv = xb[(t0 + 2 * k) * FF];
    wsum += xv; wsq = fmaf(xv, xv, wsq);
  }
  wsum += __shfl_xor(wsum, 32); wsq += __shfl_xor(wsq, 32);
  float var = (wsq - wsum * wsum * (1.f / WVOL)) * (1.f / (WVOL - 1));
  float sd = sqrtf(fmaxf(var, 0.f));
  float m = dsum64(sd) * 0.5f * (1.f / FF);
  if (lane == 0) svraw[b * SS + s] = m;
}

// ---------------- K2: per-(b,s) LN + projections + gates + zc ----------------
__global__ void k_proj(const float* __restrict__ x, const float* __restrict__ m_prev,
                       const float* __restrict__ CpT,
                       const float* __restrict__ ln_in_g, const float* __restrict__ ln_in_b,
                       const float* __restrict__ wqT, const float* __restrict__ bq,
                       const float* __restrict__ wkT, const float* __restrict__ bk,
                       const float* __restrict__ wvT, const float* __restrict__ bv,
                       const float* __restrict__ wi, const float* __restrict__ bi,
                       const float* __restrict__ wf, const float* __restrict__ bf,
                       const float* __restrict__ woT, const float* __restrict__ bo,
                       const float* __restrict__ rw1T, const float* __restrict__ rd_b1,
                       const float* __restrict__ rd_g, const float* __restrict__ rd_be,
                       const float* __restrict__ rd_w2, const float* __restrict__ rd_b2,
                       float* __restrict__ qo, float* __restrict__ kno, float* __restrict__ vno,
                       float* __restrict__ iko, float* __restrict__ oo,
                       float* __restrict__ cg_a, float* __restrict__ fg_a,
                       float* __restrict__ mf_a, float* __restrict__ cks_a,
                       float* __restrict__ qsum_a, float* __restrict__ zc) {
  int bs = blockIdx.x; int b = bs / SS;
  int lane = threadIdx.x;
  __shared__ float xs[FF];
  __shared__ float ks[DD];
  float xv = (lane < FF) ? x[bs * FF + lane] : 0.f;
  float s1x = dsum32(xv);
  float s2x = dsum32(xv * xv);
  if (lane < FF) {
    float mu = s1x * (1.f / FF);
    float var = s2x * (1.f / FF) - mu * mu;
    xs[lane] = (xv - mu) * rsqrtf(var + 1e-5f) * ln_in_g[lane] + ln_in_b[lane];
  }
  __syncthreads();
  int d = lane;
  float aq = bq[d], ak = bk[d], av = bv[d], ao = bo[d], at = rd_b1[d];
#pragma unroll
  for (int f = 0; f < FF; ++f) {
    float xf = xs[f];
    aq = fmaf(xf, wqT[f * DD + d], aq);
    ak = fmaf(xf, wkT[f * DD + d], ak);
    av = fmaf(xf, wvT[f * DD + d], av);
    ao = fmaf(xf, woT[f * DD + d], ao);
    at = fmaf(xf, rw1T[f * DD + d], at);
  }
  float pit = (lane < FF) ? xs[lane] * wi[lane] : 0.f;
  float pft = (lane < FF) ? xs[lane] * wf[lane] : 0.f;
  float itv = dsum32(pit) + bi[0];
  float ftv = dsum32(pft) + bf[0];
  float s1 = dsum64(at), s2 = dsum64(at * at);
  float mu = s1 * (1.f / DD);
  float var = s2 * (1.f / DD) - mu * mu;
  float tn = (at - mu) * rsqrtf(var + 1e-5f) * rd_g[d] + rd_be[d];
  float ge = 0.5f * tn * (1.f + erff(tn * 0.70710678118654752f));
  float l0 = dsum64(ge * rd_w2[0 * DD + d]) + rd_b2[0];
  float l1 = dsum64(ge * rd_w2[1 * DD + d]) + rd_b2[1];
  float l2 = dsum64(ge * rd_w2[2 * DD + d]) + rd_b2[2];
  float l3 = dsum64(ge * rd_w2[3 * DD + d]) + rd_b2[3];
  float mx = fmaxf(fmaxf(l0, l1), fmaxf(l2, l3));
  float e0 = expf(l0 - mx), e1 = expf(l1 - mx), e2 = expf(l2 - mx), e3 = expf(l3 - mx);
  float mfv = e0 / (e0 + e1 + e2 + e3);
  float kd = ak * 0.125f;
  float kk = dsum64(kd * kd);
  float knd = kd * (8.f / (sqrtf(kk) + 1e-12f));
  float vv = dsum64(av * av);
  float vnd = av * (8.f / (sqrtf(vv) + 1e-6f));
  float ksum = dsum64(knd);
  float qsum = dsum64(aq);
  float mp = fminf(fmaxf(m_prev[b], -100.f), 100.f);
  float mt = fmaxf(ftv, mp + ftv);
  float ig = expf(fminf(fmaxf(itv - mt, -15.f), 15.f));
  float fg = expf(fminf(fmaxf(ftv + mp - mt, -15.f), 15.f));
  float cg = fminf(ig, 1.f);
  qo[bs * DD + d] = aq;
  kno[bs * DD + d] = knd;
  vno[bs * DD + d] = vnd;
  iko[bs * DD + d] = ig * kd;
  oo[bs * DD + d] = 1.f / (1.f + expf(-ao));
  ks[d] = knd;
  __syncthreads();
  float acc = 0.f;
  const float* cpt = CpT + (size_t)b * DD * DD;
#pragma unroll 8
  for (int j = 0; j < DD; ++j) acc = fmaf(cpt[j * DD + d], ks[j], acc);
  float z = dsum64(vnd * acc);
  if (lane == 0) {
    cg_a[bs] = cg; fg_a[bs] = fg; mf_a[bs] = mfv;
    cks_a[bs] = cg * ksum; qsum_a[bs] = qsum;
    zc[bs] = cg * z;
  }
}

// -------- K3a: tiled GEMM over causal 32x32 (s,t) tile pairs ----------------
// Computes A=q.kn^T, KK=kn.kn^T, VV=vn.vn^T for the tile; writes masked
// W[s][t] = cg_t*A and atomically accumulates rho partials.
__global__ void k_qk(const float* __restrict__ qo, const float* __restrict__ kno,
                     const float* __restrict__ vno, const float* __restrict__ cg_a,
                     float* __restrict__ W, float* __restrict__ rho) {
  int blk = blockIdx.x; int b = blk / 136; int r = blk % 136;
  int st = 0;
  while ((st + 1) * (st + 2) / 2 <= r) ++st;
  int tt = r - st * (st + 1) / 2;
  int s0 = st * 32, t0 = tt * 32;
  int tid = threadIdx.x; int ty = tid >> 4, tx = tid & 15;
  __shared__ float qls[32][64], kls[32][64], vsl[32][64];   // s-side (broadcast reads)
  __shared__ float ktl[32][68], vtl[32][68];                // t-side (pad 68: 4-way max)
  __shared__ float cgl[32], sacc[32];
  {
    int col = tid & 63, rg = tid >> 6;
#pragma unroll
    for (int rr = 0; rr < 8; ++rr) {
      int row = rg * 8 + rr;
      int gi = (b * SS + s0 + row) * DD + col;
      int gj = (b * SS + t0 + row) * DD + col;
      qls[row][col] = qo[gi]; kls[row][col] = kno[gi]; vsl[row][col] = vno[gi];
      ktl[row][col] = kno[gj]; vtl[row][col] = vno[gj];
    }
    if (tid < 32) cgl[tid] = cg_a[b * SS + t0 + tid];
  }
  __syncthreads();
  float A[2][2] = {{0.f, 0.f}, {0.f, 0.f}};
  float KK[2][2] = {{0.f, 0.f}, {0.f, 0.f}};
  float VV[2][2] = {{0.f, 0.f}, {0.f, 0.f}};
  for (int k4 = 0; k4 < DD; k4 += 4) {
    float qa[2][4], ka[2][4], va[2][4], kt[2][4], vt[2][4];
#pragma unroll
    for (int i = 0; i < 2; ++i) {
      float4 t1 = *(const float4*)&qls[ty * 2 + i][k4];
      qa[i][0] = t1.x; qa[i][1] = t1.y; qa[i][2] = t1.z; qa[i][3] = t1.w;
      float4 t2 = *(const float4*)&kls[ty * 2 + i][k4];
      ka[i][0] = t2.x; ka[i][1] = t2.y; ka[i][2] = t2.z; ka[i][3] = t2.w;
      float4 t3 = *(const float4*)&vsl[ty * 2 + i][k4];
      va[i][0] = t3.x; va[i][1] = t3.y; va[i][2] = t3.z; va[i][3] = t3.w;
      float4 t4 = *(const float4*)&ktl[tx * 2 + i][k4];
      kt[i][0] = t4.x; kt[i][1] = t4.y; kt[i][2] = t4.z; kt[i][3] = t4.w;
      float4 t5 = *(const float4*)&vtl[tx * 2 + i][k4];
      vt[i][0] = t5.x; vt[i][1] = t5.y; vt[i][2] = t5.z; vt[i][3] = t5.w;
    }
#pragma unroll
    for (int kk = 0; kk < 4; ++kk)
#pragma unroll
      for (int i = 0; i < 2; ++i)
#pragma unroll
        for (int j = 0; j < 2; ++j) {
          A[i][j]  = fmaf(qa[i][kk], kt[j][kk], A[i][j]);
          KK[i][j] = fmaf(ka[i][kk], kt[j][kk], KK[i][j]);
          VV[i][j] = fmaf(va[i][kk], vt[j][kk], VV[i][j]);
        }
  }
  float cg0 = cgl[tx * 2], cg1 = cgl[tx * 2 + 1];
  int tg0 = t0 + tx * 2, tg1 = t0 + tx * 2 + 1;
#pragma unroll
  for (int i = 0; i < 2; ++i) {
    int s = s0 + ty * 2 + i;
    float w0 = (tg0 <= s) ? cg0 * A[i][0] : 0.f;
    float w1 = (tg1 <= s) ? cg1 * A[i][1] : 0.f;
    float2 wst = make_float2(w0, w1);
    *(float2*)&W[((size_t)b * SS + s) * SS + tg0] = wst;
    float wr0 = (tg0 < s) ? 2.f : (tg0 == s ? 1.f : 0.f);
    float wr1 = (tg1 < s) ? 2.f : (tg1 == s ? 1.f : 0.f);
    float rsum = dsum16(fmaf(wr0 * cg0, KK[i][0] * VV[i][0],
                             wr1 * cg1 * KK[i][1] * VV[i][1]));
    if (tx == 15) sacc[ty * 2 + i] = rsum;
  }
  __syncthreads();
  if (tid < 32) {
    int s = s0 + tid;
    atomicAdd(&rho[b * SS + s], cg_a[b * SS + s] * sacc[tid]);
  }
}

// -------- K3b: p2 = W @ vn (causal K handled by masked/zeroed W) ------------
__global__ void k_pv(const float* __restrict__ W, const float* __restrict__ vno,
                     float* __restrict__ p2) {
  int blk = blockIdx.x; int b = blk / 26; int u = blk % 26;
  int st32, c0, c1;
  if (u < 6) { st32 = u; c0 = 0; c1 = u >> 1; }
  else {
    int v = u - 6; st32 = 6 + (v >> 1);
    int nch = (st32 >> 1) + 1; int h0 = nch >> 1;
    if (v & 1) { c0 = h0; c1 = nch - 1; } else { c0 = 0; c1 = h0 - 1; }
  }
  int s0 = st32 * 32;
  int tid = threadIdx.x; int ty = tid >> 4, tx = tid & 15;
  __shared__ float wls[32][64];
  __shared__ float vls[64][64];
  float acc[2][4] = {{0.f, 0.f, 0.f, 0.f}, {0.f, 0.f, 0.f, 0.f}};
  for (int c = c0; c <= c1; ++c) {
    __syncthreads();
    int t0 = c * 64;
    int col = tid & 63, rg = tid >> 6;
#pragma unroll
    for (int rr = 0; rr < 8; ++rr) {
      int r2 = rg * 8 + rr;
      wls[r2][col] = W[((size_t)b * SS + s0 + r2) * SS + t0 + col];
    }
#pragma unroll
    for (int rr = 0; rr < 16; ++rr) {
      int t = rg * 16 + rr;
      vls[t][col] = vno[(b * SS + t0 + t) * DD + col];
    }
    __syncthreads();
    for (int k4 = 0; k4 < 64; k4 += 4) {
      float aa[2][4];
#pragma unroll
      for (int i = 0; i < 2; ++i) {
        float4 t1 = *(const float4*)&wls[ty * 2 + i][k4];
        aa[i][0] = t1.x; aa[i][1] = t1.y; aa[i][2] = t1.z; aa[i][3] = t1.w;
      }
      float bb[4][4];
#pragma unroll
      for (int kk = 0; kk < 4; ++kk) {
        float4 t2 = *(const float4*)&vls[k4 + kk][tx * 4];
        bb[kk][0] = t2.x; bb[kk][1] = t2.y; bb[kk][2] = t2.z; bb[kk][3] = t2.w;
      }
#pragma unroll
      for (int kk = 0; kk < 4; ++kk)
#pragma unroll
        for (int i = 0; i < 2; ++i)
#pragma unroll
          for (int j = 0; j < 4; ++j)
            acc[i][j] = fmaf(aa[i][kk], bb[kk][j], acc[i][j]);
    }
  }
#pragma unroll
  for (int i = 0; i < 2; ++i)
#pragma unroll
    for (int j = 0; j < 4; ++j)
      atomicAdd(&p2[(b * SS + s0 + ty * 2 + i) * DD + tx * 4 + j], acc[i][j]);
}

// ---- K4: merged: blocks 0..7 scalar scans + vol-norm; blocks 8+ chunk sums --
__global__ void k_post(const float* __restrict__ fg_a, const float* __restrict__ zc,
                       const float* __restrict__ rho, const float* __restrict__ svraw,
                       const float* __restrict__ ik, const float* __restrict__ vno,
                       const float* __restrict__ cks_a,
                       float* __restrict__ fcum, float* __restrict__ cpd,
                       float* __restrict__ sn2, float* __restrict__ sv,
                       float* __restrict__ csn, float* __restrict__ csr) {
  int blk = blockIdx.x; int lane = threadIdx.x;
  if (blk < BB) {
    int b = blk;
    float m0 = svraw[b * SS + WVOL - 1];
    float vals[8]; float part = 0.f;
#pragma unroll
    for (int c = 0; c < 8; ++c) {
      int idx = c * 64 + lane;
      float v = (idx < WVOL - 1) ? m0 : svraw[b * SS + idx];
      vals[c] = v; part += v;
    }
    float tot = dsum64(part);
    float inv = 1.f / (tot * (1.f / SS) + 1e-6f);
#pragma unroll
    for (int c = 0; c < 8; ++c) sv[b * SS + c * 64 + lane] = vals[c] * inv;
    float cf = 1.f, cz = 0.f, crr = 0.f;
    for (int c = 0; c < 8; ++c) {
      int bs = b * SS + c * 64 + lane;
      float f = dscan_mul(fg_a[bs]) * cf;
      float z = dscan_add(zc[bs]) + cz;
      float r = dscan_add(rho[bs]) + crr;
      fcum[bs] = f; cpd[bs] = z; sn2[bs] = r;
      cf = rlane(f, 63); cz = rlane(z, 63); crr = rlane(r, 63);
    }
  } else {
    int blk2 = blk - BB; int b = blk2 / NCH; int w = blk2 % NCH; int d = lane;
    float na = 0.f, ra = 0.f;
#pragma unroll
    for (int t = 0; t < CH; ++t) {
      int bs = b * SS + w * CH + t;
      na += ik[bs * DD + d];
      ra = fmaf(cks_a[bs], vno[bs * DD + d], ra);
    }
    csn[blk2 * DD + d] = na; csr[blk2 * DD + d] = ra;
  }
}

__global__ void k_scan_apply(const float* __restrict__ ik, const float* __restrict__ vno,
                             const float* __restrict__ cks_a,
                             const float* __restrict__ csn, const float* __restrict__ csr,
                             float* __restrict__ nacc, float* __restrict__ racc) {
  int blk = blockIdx.x; int b = blk / NCH; int w = blk % NCH; int d = threadIdx.x;
  float na = 0.f, ra = 0.f;
  for (int w2 = 0; w2 < w; ++w2) {
    na += csn[(b * NCH + w2) * DD + d];
    ra += csr[(b * NCH + w2) * DD + d];
  }
#pragma unroll
  for (int t = 0; t < CH; ++t) {
    int bs = b * SS + w * CH + t;
    na += ik[bs * DD + d];
    ra = fmaf(cks_a[bs], vno[bs * DD + d], ra);
    nacc[bs * DD + d] = na;
    racc[bs * DD + d] = ra;
  }
}

// ---------------- K6: SSM scan, one wave per (b, row i); tight chain ---------
__global__ void k_ssm(const float* __restrict__ fcum, const float* __restrict__ racc,
                      const float* __restrict__ cpr, const float* __restrict__ sv,
                      const float* __restrict__ log_lam, const float* __restrict__ log_b,
                      const float* __restrict__ cvec,
                      const float* __restrict__ log_step, const float* __restrict__ vol_gate,
                      const float* __restrict__ ln_g, const float* __restrict__ ln_b,
                      float* __restrict__ ysT) {
  int blk = blockIdx.x; int b = blk >> 6; int i = blk & 63;
  int n = threadIdx.x;
  float st = expf(log_step[0]);
  float lam = -expf(log_lam[n]);
  float ad = (2.f + st * lam) / (2.f - st * lam);
  float bd = st * (1.f + ad) * expf(log_b[n]) * 0.5f;
  float vg = 1.f / (1.f + expf(-vol_gate[n]));
  float g = ln_g[n], be = ln_b[n], cn = cvec[n];
  float cprv = cpr[b * DD + i];
  float u[8], w[8];
#pragma unroll
  for (int c = 0; c < 8; ++c) {
    int s = c * 64 + n; int bs = b * SS + s;
    u[c] = fmaf(fcum[bs], cprv, racc[(size_t)bs * DD + i]) * (1.f / DD);
    w[c] = sv[bs];
  }
  float h = 0.f;
#pragma unroll
  for (int c = 0; c < 8; ++c) {
    float yout = 0.f;
#pragma unroll 4
    for (int t = 0; t < 64; ++t) {
      float uu = rlane(u[c], t);
      float vv = rlane(w[c], t);
      float bdu = bd * uu;
      float rden = __builtin_amdgcn_rcpf(fmaf(vg, vv, 1.f));
      float grden = g * rden, berden = be * rden;
      float ht = fmaf(ad, h, bdu);
      float p1 = ht, p2 = ht * ht;
      p1 += updpp<0x111, 0xF, true>(0.f, p1); p2 += updpp<0x111, 0xF, true>(0.f, p2);
      p1 += updpp<0x112, 0xF, true>(0.f, p1); p2 += updpp<0x112, 0xF, true>(0.f, p2);
      p1 += updpp<0x114, 0xF, true>(0.f, p1); p2 += updpp<0x114, 0xF, true>(0.f, p2);
      p1 += updpp<0x118, 0xF, true>(0.f, p1); p2 += updpp<0x118, 0xF, true>(0.f, p2);
      p1 += updpp<0x142, 0xF, true>(0.f, p1); p2 += updpp<0x142, 0xF, true>(0.f, p2);
      p1 += updpp<0x143, 0xF, true>(0.f, p1); p2 += updpp<0x143, 0xF, true>(0.f, p2);
      float s1 = rlane(p1, 63), s2 = rlane(p2, 63);
      float mu = s1 * (1.f / DD);
      float r2m = fmaf(-mu, s1, s2);
      float arg = fmaxf(fmaf(r2m, 1.f / DD, 1e-5f), 1e-5f);
      float irs = __builtin_amdgcn_rsqf(arg);
      float hv = fmaf((ht - mu) * grden, irs, berden);
      h = hv;
      float y = cn * hv;
      y += updpp<0x111, 0xF, true>(0.f, y);
      y += updpp<0x112, 0xF, true>(0.f, y);
      y += updpp<0x114, 0xF, true>(0.f, y);
      y += updpp<0x118, 0xF, true>(0.f, y);
      y += updpp<0x142, 0xF, true>(0.f, y);
      y += updpp<0x143, 0xF, true>(0.f, y);
      float su = rlane(y, 63);
      yout = (n == t) ? su : yout;
    }
    ysT[(size_t)(b * DD + i) * SS + c * 64 + n] = yout;
  }
}

// ---------------- K7: final readout ----------------
__global__ void k_final(const float* __restrict__ qo, const float* __restrict__ oo,
                        const float* __restrict__ p2, const float* __restrict__ racc,
                        const float* __restrict__ nacc, const float* __restrict__ ysT,
                        const float* __restrict__ CpT, const float* __restrict__ cpr,
                        const float* __restrict__ cpn2,
                        const float* __restrict__ fcum, const float* __restrict__ cpd,
                        const float* __restrict__ sn2,
                        const float* __restrict__ mf_a, const float* __restrict__ qsum_a,
                        const float* __restrict__ n_prev,
                        const float* __restrict__ ssm_log_d, const float* __restrict__ ssm_alpha,
                        const float* __restrict__ ln_mem_g, const float* __restrict__ ln_mem_b,
                        float* __restrict__ out) {
  int bs = blockIdx.x; int b = bs / SS; int s = bs % SS;
  int i = threadIdx.x;
  __shared__ float qv[DD];
  float qi = qo[bs * DD + i];
  qv[i] = qi;
  __syncthreads();
  float P1 = 0.f;
  const float* cpt = CpT + (size_t)b * DD * DD;
#pragma unroll 8
  for (int j = 0; j < DD; ++j) P1 = fmaf(cpt[j * DD + i], qv[j], P1);
  float fc = fcum[bs];
  float p = fmaf(fc, P1, p2[bs * DD + i]);
  float r = fmaf(fc, cpr[b * DD + i], racc[bs * DD + i]);
  float R2 = fc * fc * cpn2[b] + 2.f * fc * cpd[bs] + sn2[bs];
  float al = 1.f / (1.f + expf(-ssm_alpha[0]));
  float kap = al + (1.f - al) * expf(ssm_log_d[0]);
  float mfv = mf_a[bs];
  float beta = 1.f + mfv * (kap - 1.f);
  float gam = mfv * (1.f - al);
  float y = ysT[(size_t)(b * DD + i) * SS + s];
  float syr = dsum64(y * r);
  float sy2 = dsum64(y * y);
  float nrm2 = fmaxf(beta * beta * R2 + 2.f * beta * gam * syr + gam * gam * (float)DD * sy2, 0.f);
  float scale = 8.f / (sqrtf(nrm2) + 1e-6f);
  float nt = fmaf(fc, n_prev[b * DD + i], nacc[bs * DD + i]);
  float ndp = dsum64(nt * qi);
  float denom = fmaxf(fabsf(ndp), 1.f);
  float hh = scale * (fmaf(beta, p, gam * y * qsum_a[bs])) / denom;
  float s1 = dsum64(hh), s2 = dsum64(hh * hh);
  float mu = s1 * (1.f / DD);
  float var = fmaxf(s2 * (1.f / DD) - mu * mu, 0.f);
  float o = (hh - mu) * rsqrtf(var + 1e-5f) * ln_mem_g[i] + ln_mem_b[i];
  out[bs * DD + i] = oo[bs * DD + i] * o;
}

extern "C" void kernel_launch(void* const* d_in, const int* in_sizes, int n_in,
                              void* d_out, int out_size, void* d_ws, size_t ws_size,
                              hipStream_t stream) {
  const float* x        = (const float*)d_in[0];
  const float* C_prev   = (const float*)d_in[1];
  const float* n_prev   = (const float*)d_in[2];
  const float* m_prev   = (const float*)d_in[3];
  const float* ln_in_g  = (const float*)d_in[4];
  const float* ln_in_b  = (const float*)d_in[5];
  const float* wq = (const float*)d_in[6];  const float* bq = (const float*)d_in[7];
  const float* wk = (const float*)d_in[8];  const float* bk = (const float*)d_in[9];
  const float* wv = (const float*)d_in[10]; const float* bv = (const float*)d_in[11];
  const float* wi = (const float*)d_in[12]; const float* bi = (const float*)d_in[13];
  const float* wf = (const float*)d_in[14]; const float* bf = (const float*)d_in[15];
  const float* wo = (const float*)d_in[16]; const float* bo = (const float*)d_in[17];
  const float* rd_w1 = (const float*)d_in[18]; const float* rd_b1 = (const float*)d_in[19];
  const float* rd_g  = (const float*)d_in[20]; const float* rd_be = (const float*)d_in[21];
  const float* rd_w2 = (const float*)d_in[22]; const float* rd_b2 = (const float*)d_in[23];
  const float* ssm_log_lam  = (const float*)d_in[24];
  const float* ssm_log_b    = (const float*)d_in[25];
  const float* ssm_c        = (const float*)d_in[26];
  const float* ssm_log_d    = (const float*)d_in[27];
  const float* ssm_log_step = (const float*)d_in[28];
  const float* ssm_vol_gate = (const float*)d_in[29];
  const float* ssm_alpha    = (const float*)d_in[30];
  const float* ssm_ln_g     = (const float*)d_in[31];
  const float* ssm_ln_b     = (const float*)d_in[32];
  const float* ln_mem_g     = (const float*)d_in[33];
  const float* ln_mem_b     = (const float*)d_in[34];
  float* out = (float*)d_out;

  float* Wsp = (float*)d_ws;
  size_t o0 = 0;
  const size_t BS = (size_t)BB * SS, BSD = BS * DD, WSZ = (size_t)BB * SS * SS;
  float* sv    = Wsp + o0; o0 += BS;
  float* svraw = Wsp + o0; o0 += BS;
  float* qo   = Wsp + o0; o0 += BSD;
  float* kno  = Wsp + o0; o0 += BSD;
  float* vno  = Wsp + o0; o0 += BSD;
  float* iko  = Wsp + o0; o0 += BSD;
  float* oo   = Wsp + o0; o0 += BSD;
  float* racc = Wsp + o0; o0 += BSD;
  float* nacc = Wsp + o0; o0 += BSD;
  float* ysT  = Wsp + o0; o0 += BSD;
  float* p2   = Wsp + o0; o0 += BSD;   // memset region start
  float* rho  = Wsp + o0; o0 += BS;
  float* Wm   = Wsp + o0; o0 += WSZ;   // memset region end
  float* cg_a = Wsp + o0; o0 += BS;
  float* fg_a = Wsp + o0; o0 += BS;
  float* mf_a = Wsp + o0; o0 += BS;
  float* cks  = Wsp + o0; o0 += BS;
  float* qsum = Wsp + o0; o0 += BS;
  float* zc   = Wsp + o0; o0 += BS;
  float* fcum = Wsp + o0; o0 += BS;
  float* cpd  = Wsp + o0; o0 += BS;
  float* sn2  = Wsp + o0; o0 += BS;
  float* cpr  = Wsp + o0; o0 += (size_t)BB * DD;
  float* cpn2 = Wsp + o0; o0 += BB;
  float* csn  = Wsp + o0; o0 += (size_t)BB * NCH * DD;
  float* csr  = Wsp + o0; o0 += (size_t)BB * NCH * DD;
  float* CpT  = Wsp + o0; o0 += (size_t)BB * DD * DD;
  float* wqT  = Wsp + o0; o0 += (size_t)FF * DD;
  float* wkT  = Wsp + o0; o0 += (size_t)FF * DD;
  float* wvT  = Wsp + o0; o0 += (size_t)FF * DD;
  float* woT  = Wsp + o0; o0 += (size_t)FF * DD;
  float* rw1T = Wsp + o0; o0 += (size_t)FF * DD;

  hipMemsetAsync(p2, 0, (BSD + BS + WSZ) * sizeof(float), stream);
  hipLaunchKernelGGL(k_prep, dim3(BB + 5), dim3(64), 0, stream,
                     C_prev, wq, wk, wv, wo, rd_w1,
                     CpT, wqT, wkT, wvT, woT, rw1T, cpr, cpn2);
  hipLaunchKernelGGL(k_vol_std, dim3(BB, SS - WVOL + 1), dim3(64), 0, stream, x, svraw);
  hipLaunchKernelGGL(k_proj, dim3(BB * SS), dim3(64), 0, stream,
                     x, m_prev, CpT, ln_in_g, ln_in_b, wqT, bq, wkT, bk, wvT, bv, wi, bi,
                     wf, bf, woT, bo, rw1T, rd_b1, rd_g, rd_be, rd_w2, rd_b2,
                     qo, kno, vno, iko, oo, cg_a, fg_a, mf_a, cks, qsum, zc);
  hipLaunchKernelGGL(k_qk, dim3(BB * 136), dim3(256), 0, stream,
                     qo, kno, vno, cg_a, Wm, rho);
  hipLaunchKernelGGL(k_pv, dim3(BB * 26), dim3(256), 0, stream, Wm, vno, p2);
  hipLaunchKernelGGL(k_post, dim3(BB + BB * NCH), dim3(64), 0, stream,
                     fg_a, zc, rho, svraw, iko, vno, cks,
                     fcum, cpd, sn2, sv, csn, csr);
  hipLaunchKernelGGL(k_scan_apply, dim3(BB * NCH), dim3(64), 0, stream,
                     iko, vno, cks, csn, csr, nacc, racc);
  hipLaunchKernelGGL(k_ssm, dim3(BB * DD), dim3(64), 0, stream,
                     fcum, racc, cpr, sv, ssm_log_lam, ssm_log_b, ssm_c,
                     ssm_log_step, ssm_vol_gate, ssm_ln_g, ssm_ln_b, ysT);
  hipLaunchKernelGGL(k_final, dim3(BB * SS), dim3(64), 0, stream,
                     qo, oo, p2, racc, nacc, ysT, CpT, cpr, cpn2, fcum, cpd, sn2,
                     mf_a, qsum, n_prev, ssm_log_d, ssm_alpha, ln_mem_g, ln_mem_b, out);
}